// Round 2
// baseline (401.217 us; speedup 1.0000x reference)
//
#include <hip/hip_runtime.h>

// Workspace float offsets
#define WS_F     0      // f[128]
#define WS_FEAT0 128    // feat0[450]
#define WS_H1    640    // h1[450]
#define WS_FEAT  1152   // feat[450]
#define WS_H2    1664   // h2[450]
#define WS_CNT   2176   // int barrier counter (zeroed via hipMemsetAsync)

// Device-scope grid barrier (monotonic counter, no reset needed within a call).
// All 128 blocks are co-resident (grid 128 << 256 CUs, 256 thr, ~6KB LDS).
__device__ __forceinline__ void gbar(int* cnt, int target) {
  __syncthreads();
  if (threadIdx.x == 0) {
    __threadfence();                 // release: flush this block's writes
    atomicAdd(cnt, 1);               // device-scope
    while (__hip_atomic_load(cnt, __ATOMIC_RELAXED, __HIP_MEMORY_SCOPE_AGENT) < target) {
      __builtin_amdgcn_s_sleep(8);
    }
    __threadfence();                 // acquire: invalidate stale cache
  }
  __syncthreads();
}

// 450x450 matvec phase: vout = [relu](W@vin + b). Wave per row.
__device__ __forceinline__ void phase_mv450(
    const float* __restrict__ W, const float* __restrict__ b,
    const float* __restrict__ vin, float* __restrict__ vout,
    int relu, float* sv) {
  const int tid = threadIdx.x;
  if (tid < 450) sv[tid] = vin[tid];
  if (tid + 256 < 450) sv[tid + 256] = vin[tid + 256];
  __syncthreads();
  const int lane = tid & 63;
  const int row = blockIdx.x * 4 + (tid >> 6);   // 0..511, guard <450
  if (row < 450) {
    const float2* Wr = (const float2*)(W + row * 450);  // 225 float2, 8B-aligned
    float acc = 0.f;
#pragma unroll
    for (int k = 0; k < 4; ++k) {
      int idx = lane + (k << 6);
      if (idx < 225) {
        float2 w = Wr[idx];
        acc += w.x * sv[2 * idx] + w.y * sv[2 * idx + 1];
      }
    }
#pragma unroll
    for (int off = 32; off > 0; off >>= 1) acc += __shfl_down(acc, off);
    if (lane == 0) {
      float r = acc + b[row];
      if (relu) r = fmaxf(r, 0.f);
      vout[row] = r;
    }
  }
}

// Fused K1..K5: f -> feat0 -> h1 -> feat -> h2, with 4 grid barriers.
__global__ __launch_bounds__(256) void k_front(
    const float* __restrict__ x, const float* __restrict__ TwE,
    const float* __restrict__ PE, const float* __restrict__ CE,
    const float* __restrict__ mE,
    const float* __restrict__ eW1, const float* __restrict__ eb1,
    const float* __restrict__ eW2, const float* __restrict__ eb2,
    const float* __restrict__ dW1, const float* __restrict__ db1,
    float* __restrict__ ws, int* __restrict__ cnt) {
  __shared__ float smem[1416];   // coef[1024] | sCE[128] | sPE[256] | sTw[4] | red[4]
  float* f     = ws + WS_F;
  float* feat0 = ws + WS_FEAT0;
  float* h1    = ws + WS_H1;
  float* feat  = ws + WS_FEAT;
  float* h2    = ws + WS_H2;
  const int tid = threadIdx.x;
  const int lane = tid & 63;

  // ---- Phase 0: f[i], i = blockIdx.x (grid = 128) ----
  {
    float* coef = smem;
    float* sCE  = smem + 1024;
    float* sPE  = smem + 1152;
    float* sTw  = smem + 1408;
    float* red  = smem + 1412;
    const int i = blockIdx.x;
    if (tid < 128) sCE[tid] = CE[tid * 128 + i];
    sPE[tid] = PE[tid * 128 + i];
    if (tid < 4) sTw[tid] = TwE[tid * 128 + i];
    __syncthreads();
#pragma unroll
    for (int k = 0; k < 4; ++k) {
      int q = tid + (k << 8);
      coef[q] = sTw[q >> 8] * sPE[q & 255];
    }
    __syncthreads();
    const int wv = tid >> 6;
    const float2 ce = ((const float2*)sCE)[lane];
    const float2* Xw = (const float2*)(x + 4 * 256 * 128);
    float acc = 0.f;
    const int q0 = wv * 256;
#pragma unroll 8
    for (int k = 0; k < 256; ++k) {
      int q = q0 + k;
      float2 v = Xw[q * 64 + lane];
      acc += coef[q] * (v.x * ce.x + v.y * ce.y);
    }
#pragma unroll
    for (int off = 32; off > 0; off >>= 1) acc += __shfl_down(acc, off);
    if (lane == 0) red[wv] = acc;
    __syncthreads();
    if (tid == 0) f[i] = red[0] + red[1] + red[2] + red[3];
  }
  gbar(cnt, 128);

  // ---- Phase 1: feat0 = mE @ f (450 rows, dot 128) ----
  {
    if (tid < 128) smem[tid] = f[tid];
    __syncthreads();
    const int row = blockIdx.x * 4 + (tid >> 6);
    if (row < 450) {
      float2 v = ((const float2*)(mE + row * 128))[lane];
      float acc = v.x * smem[2 * lane] + v.y * smem[2 * lane + 1];
#pragma unroll
      for (int off = 32; off > 0; off >>= 1) acc += __shfl_down(acc, off);
      if (lane == 0) feat0[row] = acc;
    }
  }
  gbar(cnt, 256);

  // ---- Phase 2: h1 = relu(eW1@feat0 + eb1) ----
  phase_mv450(eW1, eb1, feat0, h1, 1, smem);
  gbar(cnt, 384);

  // ---- Phase 3: feat = eW2@h1 + eb2 ----
  phase_mv450(eW2, eb2, h1, feat, 0, smem);
  gbar(cnt, 512);

  // ---- Phase 4: h2 = relu(dW1@feat + db1) ----
  phase_mv450(dW1, db1, feat, h2, 1, smem);
}

// K6: out = dec_W2 @ h2 + dec_b2. Wave per ROW-PAIR (900 floats = 225 float4,
// 16B-aligned since pair stride = 3600B). sv2 = h2 duplicated to avoid %450.
__global__ __launch_bounds__(256) void k_dec2(
    const float* __restrict__ W, const float* __restrict__ b,
    const float* __restrict__ h, float* __restrict__ out) {
  __shared__ float sv2[900];
  const int tid = threadIdx.x;
  for (int k = tid; k < 900; k += 256) sv2[k] = h[k < 450 ? k : k - 450];
  __syncthreads();
  const int lane = tid & 63;
  const int rp = blockIdx.x * 4 + (tid >> 6);    // row pair, 0..65535
  const float4* Wp = (const float4*)(W + (size_t)rp * 900);
  float accA = 0.f, accB = 0.f;
#pragma unroll
  for (int k = 0; k < 3; ++k) {
    int j = lane + (k << 6);          // 0..191
    float4 w = Wp[j];
    const float* s = &sv2[4 * j];
    float p01 = w.x * s[0] + w.y * s[1];
    float p23 = w.z * s[2] + w.w * s[3];
    if (4 * j + 3 < 450)      accA += p01 + p23;   // j <= 111
    else if (4 * j >= 450)    accB += p01 + p23;   // j >= 113
    else { accA += p01; accB += p23; }             // j == 112 straddles
  }
  if (lane < 33) {                    // j = 192..224, all row B
    int j = 192 + lane;
    float4 w = Wp[j];
    const float* s = &sv2[4 * j];
    accB += w.x * s[0] + w.y * s[1] + w.z * s[2] + w.w * s[3];
  }
#pragma unroll
  for (int off = 32; off > 0; off >>= 1) {
    accA += __shfl_down(accA, off);
    accB += __shfl_down(accB, off);
  }
  if (lane == 0) {
    int r = rp * 2;
    out[r]     = accA + b[r];
    out[r + 1] = accB + b[r + 1];
  }
}

extern "C" void kernel_launch(void* const* d_in, const int* in_sizes, int n_in,
                              void* d_out, int out_size, void* d_ws, size_t ws_size,
                              hipStream_t stream) {
  const float* x   = (const float*)d_in[0];
  const float* TwE = (const float*)d_in[2];
  const float* PE  = (const float*)d_in[3];
  const float* CE  = (const float*)d_in[4];
  const float* mE  = (const float*)d_in[5];
  const float* eW1 = (const float*)d_in[6];
  const float* eb1 = (const float*)d_in[7];
  const float* eW2 = (const float*)d_in[8];
  const float* eb2 = (const float*)d_in[9];
  const float* dW1 = (const float*)d_in[10];
  const float* db1 = (const float*)d_in[11];
  const float* dW2 = (const float*)d_in[12];
  const float* db2 = (const float*)d_in[13];
  float* out = (float*)d_out;
  float* ws  = (float*)d_ws;
  int* cnt   = (int*)(ws + WS_CNT);

  hipMemsetAsync((void*)cnt, 0, sizeof(int), stream);  // zero barrier counter
  k_front<<<128,   256, 0, stream>>>(x, TwE, PE, CE, mE, eW1, eb1, eW2, eb2,
                                     dW1, db1, ws, cnt);
  k_dec2 <<<16384, 256, 0, stream>>>(dW2, db2, ws + WS_H2, out);
}